// Round 3
// baseline (66355.865 us; speedup 1.0000x reference)
//
#include <hip/hip_runtime.h>

constexpr double PI2 = 6.283185307179586476925286766559;

// B=16, D=32, H=W=256, M=12, L=4
// ws (floats): cs2d(512 doubles=1024f) | z[33554432] | fc[294912] | fm[294912]
//              | gy[3145728] | bn[64]

__global__ __launch_bounds__(256) void k_init(double* __restrict__ cs2d) {
  int t = threadIdx.x;
  double a = PI2 * (double)t / 256.0;
  cs2d[2*t]   = cos(a);
  cs2d[2*t+1] = sin(a);
}

// h0[b,d,y,x] = w_in[d,0]*x + w_in[d,1]*c0 + w_in[d,2]*c1 + b_in[d]
__global__ __launch_bounds__(256) void k_embed(
    const float* __restrict__ xin, const float* __restrict__ coords,
    const float* __restrict__ w_in, const float* __restrict__ b_in,
    float* __restrict__ h)
{
  __shared__ float wl[96], bl[32];
  const int tid = threadIdx.x;
  if (tid < 96) wl[tid] = w_in[tid];
  if (tid >= 96 && tid < 128) bl[tid-96] = b_in[tid-96];
  __syncthreads();
  const int b = blockIdx.x >> 8, y = blockIdx.x & 255;
  const int x = tid;
  const float xv = xin[(b*256 + y)*256 + x];
  const float c0 = coords[y*256 + x];
  const float c1 = coords[65536 + y*256 + x];
  #pragma unroll 8
  for (int d = 0; d < 32; ++d) {
    h[((b*32 + d)*256 + y)*256 + x] =
        wl[3*d]*xv + wl[3*d+1]*c0 + wl[3*d+2]*c1 + bl[d];
  }
}

// NAIVE forward 2D partial DFT (with BN affine applied on read):
// fc[b,ky,kx,i] = sum_{y,x} (z*sc+bias) * e^{-2pi i (kyv*y + kx*x)/256}
// block = (b,ky,kx); thread: i = tid>>3, y-partition = tid&7
__global__ __launch_bounds__(256) void n_fwd(
    const float* __restrict__ z, const double* __restrict__ cs2d,
    const float* __restrict__ bnp, float* __restrict__ fc)
{
  const int bid = blockIdx.x;
  const int kx = bid % 12, t2 = bid / 12;
  const int ky = t2 % 24, b = t2 / 24;
  const int kyv = (ky < 12) ? ky : (232 + ky);
  const int tid = threadIdx.x;
  const int i = tid >> 3, part = tid & 7;
  const double sc   = bnp ? (double)bnp[i]      : 1.0;
  const double bias = bnp ? (double)bnp[32 + i] : 0.0;
  double ar = 0.0, ai = 0.0;
  for (int y = part; y < 256; y += 8) {
    const float* row = z + (((long)(b*32 + i))*256 + y)*256;
    int t = (kyv * y) & 255;
    for (int x = 0; x < 256; ++x) {
      double v = (double)row[x] * sc + bias;
      double c = cs2d[2*t], sn = cs2d[2*t+1];
      ar += v * c;
      ai -= v * sn;
      t = (t + kx) & 255;
    }
  }
  #pragma unroll
  for (int m = 1; m < 8; m <<= 1) {
    ar += __shfl_xor(ar, m, 64);
    ai += __shfl_xor(ai, m, 64);
  }
  if (part == 0) {
    float* o = fc + ((b*24 + ky)*12 + kx)*64 + 2*i;
    o[0] = (float)ar;
    o[1] = (float)ai;
  }
}

// NAIVE per-mode complex channel mix: one thread per (b,o,ky,kx)
__global__ __launch_bounds__(256) void n_mix(
    const float* __restrict__ fc, float* __restrict__ fm,
    const float* __restrict__ w1r, const float* __restrict__ w1i,
    const float* __restrict__ w2r, const float* __restrict__ w2i)
{
  const int T = blockIdx.x*256 + threadIdx.x;     // [0, 147456)
  const int b = T / 9216;
  const int r = T % 9216;
  const int ky = r / 384;
  const int r2 = r % 384;
  const int kx = r2 / 32, o = r2 % 32;
  const float* wr_ = (ky < 12) ? w1r : w2r;
  const float* wi_ = (ky < 12) ? w1i : w2i;
  const int kyp = (ky < 12) ? ky : ky - 12;
  const float* fin = fc + ((b*24 + ky)*12 + kx)*64;
  double ar = 0.0, ai = 0.0;
  for (int i = 0; i < 32; ++i) {
    double fr = fin[2*i], fi = fin[2*i+1];
    double wr = wr_[(i*32 + o)*144 + kyp*12 + kx];
    double wi = wi_[(i*32 + o)*144 + kyp*12 + kx];
    ar += fr*wr - fi*wi;
    ai += fr*wi + fi*wr;
  }
  float* op = fm + ((b*24 + ky)*12 + kx)*64 + 2*o;
  op[0] = (float)ar;
  op[1] = (float)ai;
}

// NAIVE inverse DFT along y (full complex, 1/(H*W) folded):
// gy[b,y,kx,o] = (1/65536) * sum_s fm[b,s,kx,o] * e^{+2pi i kyv(s) y/256}
__global__ __launch_bounds__(256) void n_inv_y(
    const float* __restrict__ fm, const double* __restrict__ cs2d,
    float* __restrict__ gy)
{
  const int b = blockIdx.x >> 8, y = blockIdx.x & 255;
  const int tid = threadIdx.x;
  for (int j = tid; j < 384; j += 256) {
    const int kx = j >> 5, o = j & 31;
    double ar = 0.0, ai = 0.0;
    for (int s = 0; s < 24; ++s) {
      const int kyv = (s < 12) ? s : (232 + s);
      const int idx = (kyv * y) & 255;
      double c = cs2d[2*idx], sn = cs2d[2*idx+1];
      double fr = fm[((b*24 + s)*12 + kx)*64 + 2*o];
      double fi = fm[((b*24 + s)*12 + kx)*64 + 2*o + 1];
      ar += fr*c - fi*sn;
      ai += fr*sn + fi*c;
    }
    float* op = gy + ((b*256 + y)*12 + kx)*64 + 2*o;
    op[0] = (float)(ar * (1.0/65536.0));
    op[1] = (float)(ai * (1.0/65536.0));
  }
}

// NAIVE inverse x (c2r) + residual pointwise linear + ReLU -> z
// block=(b,y), thread=x
__global__ __launch_bounds__(256) void n_epi(
    const float* __restrict__ gy, const double* __restrict__ cs2d,
    const float* __restrict__ lw, const float* __restrict__ lb,
    float* __restrict__ z)
{
  const int b = blockIdx.x >> 8, y = blockIdx.x & 255;
  const int tid = threadIdx.x;
  __shared__ float G[768];
  __shared__ float lwl[1024];
  __shared__ float lbl[32];
  for (int f = tid; f < 768; f += 256)  G[f]   = gy[(b*256 + y)*768 + f];
  for (int f = tid; f < 1024; f += 256) lwl[f] = lw[f];
  if (tid < 32) lbl[tid] = lb[tid];
  __syncthreads();
  const int x = tid;
  double tc[12], tsn[12];
  for (int kx = 1; kx < 12; ++kx) {
    int idx = (kx * x) & 255;
    tc[kx]  = 2.0 * cs2d[2*idx];
    tsn[kx] = 2.0 * cs2d[2*idx+1];
  }
  double yv[32];
  for (int o = 0; o < 32; ++o) {
    double acc = (double)G[2*o];            // kx=0: Re only (c2r semantics)
    for (int kx = 1; kx < 12; ++kx)
      acc += (double)G[kx*64 + 2*o]*tc[kx] - (double)G[kx*64 + 2*o + 1]*tsn[kx];
    yv[o] = acc;
  }
  for (int o = 0; o < 32; ++o) {
    double a = (double)lbl[o] + yv[o];
    for (int c = 0; c < 32; ++c) a += yv[c] * (double)lwl[o*32 + c];
    double zv = (a > 0.0) ? a : 0.0;
    z[((b*32 + o)*256 + y)*256 + x] = (float)zv;
  }
}

// NAIVE BN stats: block = channel c; double accumulation over 1M elements
__global__ __launch_bounds__(256) void n_stat(
    const float* __restrict__ z, const float* __restrict__ gamma,
    const float* __restrict__ beta, float* __restrict__ bn)
{
  const int c = blockIdx.x, tid = threadIdx.x;
  double s1 = 0.0, s2 = 0.0;
  for (int i = tid; i < 1048576; i += 256) {
    int b = i >> 16, p = i & 65535;
    double v = (double)z[((long)(b*32 + c))*65536 + p];
    s1 += v;
    s2 += v*v;
  }
  __shared__ double rd1[256], rd2[256];
  rd1[tid] = s1; rd2[tid] = s2;
  __syncthreads();
  for (int off = 128; off; off >>= 1) {
    if (tid < off) { rd1[tid] += rd1[tid+off]; rd2[tid] += rd2[tid+off]; }
    __syncthreads();
  }
  if (tid == 0) {
    const double N = 1048576.0;
    double mean = rd1[0] / N;
    double var  = rd2[0] / N - mean*mean;
    double inv  = 1.0 / sqrt(var + 1e-5);
    double scd  = (double)gamma[c] * inv;
    bn[c]      = (float)scd;
    bn[32 + c] = (float)((double)beta[c] - mean*scd);
  }
}

// Final: BN affine (layer 3) + linear_out
__global__ __launch_bounds__(256) void k_out(
    const float* __restrict__ z, const float* __restrict__ bn,
    const float* __restrict__ w_out, const float* __restrict__ b_out,
    float* __restrict__ out)
{
  __shared__ float a[32];
  __shared__ float c0s;
  const int tid = threadIdx.x;
  if (tid < 32) a[tid] = bn[tid] * w_out[tid];
  if (tid == 0) {
    float t = b_out[0];
    for (int c = 0; c < 32; ++c) t += bn[32 + c] * w_out[c];
    c0s = t;
  }
  __syncthreads();
  int gid = blockIdx.x*256 + tid;             // [0, 262144)
  int b = gid >> 14, pos = (gid & 16383) << 2;
  const float* zb = z + (long)b*2097152 + pos;
  float c0 = c0s;
  float r0 = c0, r1 = c0, r2 = c0, r3 = c0;
  #pragma unroll 8
  for (int c = 0; c < 32; ++c) {
    float4 v = *(const float4*)(zb + c*65536);
    float ac = a[c];
    r0 += v.x*ac; r1 += v.y*ac; r2 += v.z*ac; r3 += v.w*ac;
  }
  float4 res; res.x = r0; res.y = r1; res.z = r2; res.w = r3;
  *(float4*)(out + (long)b*65536 + pos) = res;
}

extern "C" void kernel_launch(void* const* d_in, const int* in_sizes, int n_in,
                              void* d_out, int out_size, void* d_ws, size_t ws_size,
                              hipStream_t stream) {
  const float* x      = (const float*)d_in[0];
  const float* coords = (const float*)d_in[1];
  const float* w_in   = (const float*)d_in[2];
  const float* b_in   = (const float*)d_in[3];
  const float* w1r    = (const float*)d_in[4];
  const float* w1i    = (const float*)d_in[5];
  const float* w2r    = (const float*)d_in[6];
  const float* w2i    = (const float*)d_in[7];
  const float* lw     = (const float*)d_in[8];
  const float* lb     = (const float*)d_in[9];
  const float* gamma  = (const float*)d_in[10];
  const float* beta   = (const float*)d_in[11];
  const float* w_out  = (const float*)d_in[12];
  const float* b_out  = (const float*)d_in[13];
  float* out = (float*)d_out;
  float* ws  = (float*)d_ws;

  double* cs2d = (double*)ws;          // 512 doubles = 1024 floats
  float* z  = ws + 1024;
  float* fc = z + 33554432;
  float* fm = fc + 294912;
  float* gy = fm + 294912;
  float* bn = gy + 3145728;

  k_init<<<1, 256, 0, stream>>>(cs2d);
  k_embed<<<4096, 256, 0, stream>>>(x, coords, w_in, b_in, z);

  for (int l = 0; l < 4; ++l) {
    n_fwd<<<4608, 256, 0, stream>>>(z, cs2d, (l == 0) ? nullptr : bn, fc);
    n_mix<<<576, 256, 0, stream>>>(fc, fm, w1r + l*147456, w1i + l*147456,
                                   w2r + l*147456, w2i + l*147456);
    n_inv_y<<<4096, 256, 0, stream>>>(fm, cs2d, gy);
    n_epi<<<4096, 256, 0, stream>>>(gy, cs2d, lw + l*1024, lb + l*32, z);
    n_stat<<<32, 256, 0, stream>>>(z, gamma + l*32, beta + l*32, bn);
  }

  k_out<<<1024, 256, 0, stream>>>(z, bn, w_out, b_out, out);
}

// Round 5
// 6163.349 us; speedup vs baseline: 10.7662x; 10.7662x over previous
//
#include <hip/hip_runtime.h>

constexpr double PI2 = 6.283185307179586476925286766559;

// B=16, D=32, H=W=256, M=12, L=4
// ws: cs2d(512 dbl=1024f) | cs[512] | z[33554432] | gxy[3145728] | fc[294912]
//     | fm[294912] | bn[64]    (gx and gy share gxy: disjoint lifetimes)

__global__ __launch_bounds__(256) void k_init(double* __restrict__ cs2d,
                                              float* __restrict__ cs) {
  int t = threadIdx.x;
  double a = PI2 * (double)t / 256.0;
  double c = cos(a), s = sin(a);
  cs2d[2*t]   = c;
  cs2d[2*t+1] = s;
  cs[2*t]     = (float)c;
  cs[2*t+1]   = (float)s;
}

// h0[b,d,y,x] = w_in[d,0]*x + w_in[d,1]*c0 + w_in[d,2]*c1 + b_in[d]
__global__ __launch_bounds__(256) void k_embed(
    const float* __restrict__ xin, const float* __restrict__ coords,
    const float* __restrict__ w_in, const float* __restrict__ b_in,
    float* __restrict__ h)
{
  __shared__ float wl[96], bl[32];
  const int tid = threadIdx.x;
  if (tid < 96) wl[tid] = w_in[tid];
  if (tid >= 96 && tid < 128) bl[tid-96] = b_in[tid-96];
  __syncthreads();
  const int b = blockIdx.x >> 8, y = blockIdx.x & 255;
  const int x = tid;
  const float xv = xin[(b*256 + y)*256 + x];
  const float c0 = coords[y*256 + x];
  const float c1 = coords[65536 + y*256 + x];
  #pragma unroll 8
  for (int d = 0; d < 32; ++d) {
    h[((b*32 + d)*256 + y)*256 + x] =
        wl[3*d]*xv + wl[3*d+1]*c0 + wl[3*d+2]*c1 + bl[d];
  }
}

// OPTIMIZED forward DFT along x (under test this round):
// rows of 256 reals -> 12 complex modes; gx[bc][2kx+comp][y]
__global__ __launch_bounds__(256) void k_fwd_x(
    const float* __restrict__ src, const float* __restrict__ cs,
    const float* __restrict__ bn, float* __restrict__ gx)
{
  __shared__ __align__(16) float A[32*260];
  __shared__ __align__(16) float csl[512];
  const int tid = threadIdx.x;
  const int row0 = blockIdx.x * 32;
  for (int f = tid; f < 512; f += 256) csl[f] = cs[f];
  float scale = 1.0f, bias = 0.0f;
  if (bn) {
    int c = (row0 >> 8) & 31;
    scale = bn[c]; bias = bn[32 + c];
  }
  const float* base = src + row0*256;
  for (int i = 0; i < 8; ++i) {
    int f4 = tid + i*256;                 // [0,2048) float4 index
    int r = f4 >> 6, x = (f4 & 63) << 2;
    float4 v = *(const float4*)(base + 4*f4);
    v.x = v.x*scale + bias; v.y = v.y*scale + bias;
    v.z = v.z*scale + bias; v.w = v.w*scale + bias;
    *(float4*)(&A[r*260 + x]) = v;
  }
  __syncthreads();
  if (tid < 192) {
    const int r2 = tid / 12, kx = tid % 12;
    const float* A0 = &A[(2*r2)*260];
    const float* A1 = A0 + 260;
    float arA = 0.f, aiA = 0.f, arB = 0.f, aiB = 0.f;
    int tt = 0;
    for (int x4 = 0; x4 < 64; ++x4) {
      float4 va = *(const float4*)(A0 + 4*x4);
      float4 vb = *(const float4*)(A1 + 4*x4);
      float c0, s0;
      c0 = csl[2*tt]; s0 = csl[2*tt+1]; tt = (tt + kx) & 255;
      arA += va.x*c0; aiA -= va.x*s0; arB += vb.x*c0; aiB -= vb.x*s0;
      c0 = csl[2*tt]; s0 = csl[2*tt+1]; tt = (tt + kx) & 255;
      arA += va.y*c0; aiA -= va.y*s0; arB += vb.y*c0; aiB -= vb.y*s0;
      c0 = csl[2*tt]; s0 = csl[2*tt+1]; tt = (tt + kx) & 255;
      arA += va.z*c0; aiA -= va.z*s0; arB += vb.z*c0; aiB -= vb.z*s0;
      c0 = csl[2*tt]; s0 = csl[2*tt+1]; tt = (tt + kx) & 255;
      arA += va.w*c0; aiA -= va.w*s0; arB += vb.w*c0; aiB -= vb.w*s0;
    }
    int gr = row0 + 2*r2;
    int bc = gr >> 8, yy = gr & 255;
    float* o0 = gx + (bc*24 + 2*kx)*256;
    o0[yy]           = arA;
    o0[256 + yy]     = aiA;
    o0[yy + 1]       = arB;
    o0[256 + yy + 1] = aiB;
  }
}

// NAIVE forward DFT along y (exact): reads gx[bc][2kx+comp][y], writes fc.
// one thread per (b,ky,kx,ch)
__global__ __launch_bounds__(256) void n_fwd_y(
    const float* __restrict__ gx, const double* __restrict__ cs2d,
    float* __restrict__ fc)
{
  const int T = blockIdx.x*256 + threadIdx.x;   // [0,147456)
  const int ch = T & 31;
  const int kx = (T >> 5) % 12;
  const int r  = (T >> 5) / 12;                 // b*24 + ky
  const int ky = r % 24, b = r / 24;
  const int kyv = (ky < 12) ? ky : (232 + ky);
  const int bc = b*32 + ch;
  const float* rr = gx + (bc*24 + 2*kx)*256;
  double ar = 0.0, ai = 0.0;
  for (int y = 0; y < 256; ++y) {
    int idx = (kyv * y) & 255;
    double c = cs2d[2*idx], sn = cs2d[2*idx+1];
    double vr = rr[y], vi = rr[256 + y];
    ar += vr*c + vi*sn;       // v * e^{-i theta}
    ai += vi*c - vr*sn;
  }
  float* o = fc + ((b*24 + ky)*12 + kx)*64 + 2*ch;
  o[0] = (float)ar; o[1] = (float)ai;
}

// NAIVE per-mode complex channel mix: one thread per (b,o,ky,kx)
__global__ __launch_bounds__(256) void n_mix(
    const float* __restrict__ fc, float* __restrict__ fm,
    const float* __restrict__ w1r, const float* __restrict__ w1i,
    const float* __restrict__ w2r, const float* __restrict__ w2i)
{
  const int T = blockIdx.x*256 + threadIdx.x;     // [0, 147456)
  const int b = T / 9216;
  const int r = T % 9216;
  const int ky = r / 384;
  const int r2 = r % 384;
  const int kx = r2 / 32, o = r2 % 32;
  const float* wr_ = (ky < 12) ? w1r : w2r;
  const float* wi_ = (ky < 12) ? w1i : w2i;
  const int kyp = (ky < 12) ? ky : ky - 12;
  const float* fin = fc + ((b*24 + ky)*12 + kx)*64;
  double ar = 0.0, ai = 0.0;
  for (int i = 0; i < 32; ++i) {
    double fr = fin[2*i], fi = fin[2*i+1];
    double wr = wr_[(i*32 + o)*144 + kyp*12 + kx];
    double wi = wi_[(i*32 + o)*144 + kyp*12 + kx];
    ar += fr*wr - fi*wi;
    ai += fr*wi + fi*wr;
  }
  float* op = fm + ((b*24 + ky)*12 + kx)*64 + 2*o;
  op[0] = (float)ar;
  op[1] = (float)ai;
}

// NAIVE inverse DFT along y (full complex, 1/(H*W) folded):
__global__ __launch_bounds__(256) void n_inv_y(
    const float* __restrict__ fm, const double* __restrict__ cs2d,
    float* __restrict__ gy)
{
  const int b = blockIdx.x >> 8, y = blockIdx.x & 255;
  const int tid = threadIdx.x;
  for (int j = tid; j < 384; j += 256) {
    const int kx = j >> 5, o = j & 31;
    double ar = 0.0, ai = 0.0;
    for (int s = 0; s < 24; ++s) {
      const int kyv = (s < 12) ? s : (232 + s);
      const int idx = (kyv * y) & 255;
      double c = cs2d[2*idx], sn = cs2d[2*idx+1];
      double fr = fm[((b*24 + s)*12 + kx)*64 + 2*o];
      double fi = fm[((b*24 + s)*12 + kx)*64 + 2*o + 1];
      ar += fr*c - fi*sn;
      ai += fr*sn + fi*c;
    }
    float* op = gy + ((b*256 + y)*12 + kx)*64 + 2*o;
    op[0] = (float)(ar * (1.0/65536.0));
    op[1] = (float)(ai * (1.0/65536.0));
  }
}

// NAIVE inverse x (c2r) + residual pointwise linear + ReLU -> z
__global__ __launch_bounds__(256) void n_epi(
    const float* __restrict__ gy, const double* __restrict__ cs2d,
    const float* __restrict__ lw, const float* __restrict__ lb,
    float* __restrict__ z)
{
  const int b = blockIdx.x >> 8, y = blockIdx.x & 255;
  const int tid = threadIdx.x;
  __shared__ float G[768];
  __shared__ float lwl[1024];
  __shared__ float lbl[32];
  for (int f = tid; f < 768; f += 256)  G[f]   = gy[(b*256 + y)*768 + f];
  for (int f = tid; f < 1024; f += 256) lwl[f] = lw[f];
  if (tid < 32) lbl[tid] = lb[tid];
  __syncthreads();
  const int x = tid;
  double tc[12], tsn[12];
  for (int kx = 1; kx < 12; ++kx) {
    int idx = (kx * x) & 255;
    tc[kx]  = 2.0 * cs2d[2*idx];
    tsn[kx] = 2.0 * cs2d[2*idx+1];
  }
  double yv[32];
  for (int o = 0; o < 32; ++o) {
    double acc = (double)G[2*o];            // kx=0: Re only (c2r semantics)
    for (int kx = 1; kx < 12; ++kx)
      acc += (double)G[kx*64 + 2*o]*tc[kx] - (double)G[kx*64 + 2*o + 1]*tsn[kx];
    yv[o] = acc;
  }
  for (int o = 0; o < 32; ++o) {
    double a = (double)lbl[o] + yv[o];
    for (int c = 0; c < 32; ++c) a += yv[c] * (double)lwl[o*32 + c];
    double zv = (a > 0.0) ? a : 0.0;
    z[((b*32 + o)*256 + y)*256 + x] = (float)zv;
  }
}

// NAIVE BN stats: block = channel c; double accumulation over 1M elements
__global__ __launch_bounds__(256) void n_stat(
    const float* __restrict__ z, const float* __restrict__ gamma,
    const float* __restrict__ beta, float* __restrict__ bn)
{
  const int c = blockIdx.x, tid = threadIdx.x;
  double s1 = 0.0, s2 = 0.0;
  for (int i = tid; i < 1048576; i += 256) {
    int b = i >> 16, p = i & 65535;
    double v = (double)z[((long)(b*32 + c))*65536 + p];
    s1 += v;
    s2 += v*v;
  }
  __shared__ double rd1[256], rd2[256];
  rd1[tid] = s1; rd2[tid] = s2;
  __syncthreads();
  for (int off = 128; off; off >>= 1) {
    if (tid < off) { rd1[tid] += rd1[tid+off]; rd2[tid] += rd2[tid+off]; }
    __syncthreads();
  }
  if (tid == 0) {
    const double N = 1048576.0;
    double mean = rd1[0] / N;
    double var  = rd2[0] / N - mean*mean;
    double inv  = 1.0 / sqrt(var + 1e-5);
    double scd  = (double)gamma[c] * inv;
    bn[c]      = (float)scd;
    bn[32 + c] = (float)((double)beta[c] - mean*scd);
  }
}

// Final: BN affine (layer 3) + linear_out
__global__ __launch_bounds__(256) void k_out(
    const float* __restrict__ z, const float* __restrict__ bn,
    const float* __restrict__ w_out, const float* __restrict__ b_out,
    float* __restrict__ out)
{
  __shared__ float a[32];
  __shared__ float c0s;
  const int tid = threadIdx.x;
  if (tid < 32) a[tid] = bn[tid] * w_out[tid];
  if (tid == 0) {
    float t = b_out[0];
    for (int c = 0; c < 32; ++c) t += bn[32 + c] * w_out[c];
    c0s = t;
  }
  __syncthreads();
  int gid = blockIdx.x*256 + tid;             // [0, 262144)
  int b = gid >> 14, pos = (gid & 16383) << 2;
  const float* zb = z + (long)b*2097152 + pos;
  float c0 = c0s;
  float r0 = c0, r1 = c0, r2 = c0, r3 = c0;
  #pragma unroll 8
  for (int c = 0; c < 32; ++c) {
    float4 v = *(const float4*)(zb + c*65536);
    float ac = a[c];
    r0 += v.x*ac; r1 += v.y*ac; r2 += v.z*ac; r3 += v.w*ac;
  }
  float4 res; res.x = r0; res.y = r1; res.z = r2; res.w = r3;
  *(float4*)(out + (long)b*65536 + pos) = res;
}

extern "C" void kernel_launch(void* const* d_in, const int* in_sizes, int n_in,
                              void* d_out, int out_size, void* d_ws, size_t ws_size,
                              hipStream_t stream) {
  const float* x      = (const float*)d_in[0];
  const float* coords = (const float*)d_in[1];
  const float* w_in   = (const float*)d_in[2];
  const float* b_in   = (const float*)d_in[3];
  const float* w1r    = (const float*)d_in[4];
  const float* w1i    = (const float*)d_in[5];
  const float* w2r    = (const float*)d_in[6];
  const float* w2i    = (const float*)d_in[7];
  const float* lw     = (const float*)d_in[8];
  const float* lb     = (const float*)d_in[9];
  const float* gamma  = (const float*)d_in[10];
  const float* beta   = (const float*)d_in[11];
  const float* w_out  = (const float*)d_in[12];
  const float* b_out  = (const float*)d_in[13];
  float* out = (float*)d_out;
  float* ws  = (float*)d_ws;

  double* cs2d = (double*)ws;          // 512 doubles = 1024 floats
  float* cs  = ws + 1024;              // 512 floats
  float* z   = cs + 512;
  float* gxy = z + 33554432;           // shared by gx (fwd) and gy (inv)
  float* fc  = gxy + 3145728;
  float* fm  = fc + 294912;
  float* bn  = fm + 294912;

  k_init<<<1, 256, 0, stream>>>(cs2d, cs);
  k_embed<<<4096, 256, 0, stream>>>(x, coords, w_in, b_in, z);

  for (int l = 0; l < 4; ++l) {
    k_fwd_x<<<4096, 256, 0, stream>>>(z, cs, (l == 0) ? nullptr : bn, gxy);
    n_fwd_y<<<576, 256, 0, stream>>>(gxy, cs2d, fc);
    n_mix<<<576, 256, 0, stream>>>(fc, fm, w1r + l*147456, w1i + l*147456,
                                   w2r + l*147456, w2i + l*147456);
    n_inv_y<<<4096, 256, 0, stream>>>(fm, cs2d, gxy);
    n_epi<<<4096, 256, 0, stream>>>(gxy, cs2d, lw + l*1024, lb + l*32, z);
    n_stat<<<32, 256, 0, stream>>>(z, gamma + l*32, beta + l*32, bn);
  }

  k_out<<<1024, 256, 0, stream>>>(z, bn, w_out, b_out, out);
}

// Round 7
// 900.886 us; speedup vs baseline: 73.6562x; 6.8414x over previous
//
#include <hip/hip_runtime.h>

constexpr double PI2 = 6.283185307179586476925286766559;
constexpr float INV_HW = 1.0f / 65536.0f;

// B=16, D=32, H=W=256, M=12, L=4
// ws (floats), total 37,290,560 (142.25 MiB):
//   cs[512] | z[33554432] | gxy[3145728] | fc[294912] | fm[294912] | bn[64]
//   part (262144) ALIASES fc (disjoint lifetimes); gx/gy share gxy.

__global__ __launch_bounds__(256) void k_init(float* __restrict__ cs) {
  int t = threadIdx.x;
  double a = PI2 * (double)t / 256.0;
  cs[2*t]   = (float)cos(a);
  cs[2*t+1] = (float)sin(a);
}

// h0[b,d,y,x] = w_in[d,0]*x + w_in[d,1]*c0 + w_in[d,2]*c1 + b_in[d]
__global__ __launch_bounds__(256) void k_embed(
    const float* __restrict__ xin, const float* __restrict__ coords,
    const float* __restrict__ w_in, const float* __restrict__ b_in,
    float* __restrict__ h)
{
  __shared__ float wl[96], bl[32];
  const int tid = threadIdx.x;
  if (tid < 96) wl[tid] = w_in[tid];
  if (tid >= 96 && tid < 128) bl[tid-96] = b_in[tid-96];
  __syncthreads();
  const int b = blockIdx.x >> 8, y = blockIdx.x & 255;
  const int x = tid;
  const float xv = xin[(b*256 + y)*256 + x];
  const float c0 = coords[y*256 + x];
  const float c1 = coords[65536 + y*256 + x];
  #pragma unroll 8
  for (int d = 0; d < 32; ++d) {
    h[((b*32 + d)*256 + y)*256 + x] =
        wl[3*d]*xv + wl[3*d+1]*c0 + wl[3*d+2]*c1 + bl[d];
  }
}

// Forward DFT along x: rows of 256 reals -> 12 complex modes.
// gx layout [bc][2kx+comp][y]. bn==nullptr -> identity affine.
__global__ __launch_bounds__(256) void k_fwd_x(
    const float* __restrict__ src, const float* __restrict__ cs,
    const float* __restrict__ bn, float* __restrict__ gx)
{
  __shared__ __align__(16) float A[32*260];
  __shared__ __align__(16) float csl[512];
  const int tid = threadIdx.x;
  const int row0 = blockIdx.x * 32;
  for (int f = tid; f < 512; f += 256) csl[f] = cs[f];
  float scale = 1.0f, bias = 0.0f;
  if (bn) {
    int c = (row0 >> 8) & 31;
    scale = bn[c]; bias = bn[32 + c];
  }
  const float* base = src + row0*256;
  for (int i = 0; i < 8; ++i) {
    int f4 = tid + i*256;                 // [0,2048) float4 index
    int r = f4 >> 6, x = (f4 & 63) << 2;
    float4 v = *(const float4*)(base + 4*f4);
    v.x = v.x*scale + bias; v.y = v.y*scale + bias;
    v.z = v.z*scale + bias; v.w = v.w*scale + bias;
    *(float4*)(&A[r*260 + x]) = v;
  }
  __syncthreads();
  if (tid < 192) {
    const int r2 = tid / 12, kx = tid % 12;
    const float* A0 = &A[(2*r2)*260];
    const float* A1 = A0 + 260;
    float arA = 0.f, aiA = 0.f, arB = 0.f, aiB = 0.f;
    int tt = 0;
    for (int x4 = 0; x4 < 64; ++x4) {
      float4 va = *(const float4*)(A0 + 4*x4);
      float4 vb = *(const float4*)(A1 + 4*x4);
      float c0, s0;
      c0 = csl[2*tt]; s0 = csl[2*tt+1]; tt = (tt + kx) & 255;
      arA += va.x*c0; aiA -= va.x*s0; arB += vb.x*c0; aiB -= vb.x*s0;
      c0 = csl[2*tt]; s0 = csl[2*tt+1]; tt = (tt + kx) & 255;
      arA += va.y*c0; aiA -= va.y*s0; arB += vb.y*c0; aiB -= vb.y*s0;
      c0 = csl[2*tt]; s0 = csl[2*tt+1]; tt = (tt + kx) & 255;
      arA += va.z*c0; aiA -= va.z*s0; arB += vb.z*c0; aiB -= vb.z*s0;
      c0 = csl[2*tt]; s0 = csl[2*tt+1]; tt = (tt + kx) & 255;
      arA += va.w*c0; aiA -= va.w*s0; arB += vb.w*c0; aiB -= vb.w*s0;
    }
    int gr = row0 + 2*r2;
    int bc = gr >> 8, yy = gr & 255;
    float* o0 = gx + (bc*24 + 2*kx)*256;
    o0[yy]           = arA;
    o0[256 + yy]     = aiA;
    o0[yy + 1]       = arB;
    o0[256 + yy + 1] = aiB;
  }
}

// Forward DFT along y: 256 complex -> 24 modes (ky 0..11, 244..255)
// fc layout [b][ky24][kx12][C32][2]
__global__ __launch_bounds__(256) void k_fwd_y(
    const float* __restrict__ gx, const float* __restrict__ cs,
    float* __restrict__ fc)
{
  __shared__ __align__(16) float R[8*528];
  __shared__ __align__(16) float csl[512];
  const int tid = threadIdx.x;
  for (int f = tid; f < 512; f += 256) csl[f] = cs[f];
  const int g = tid >> 5, s = tid & 31;
  const int task = blockIdx.x*8 + g;        // [0, 6144)
  {
    int bc = task / 12, kx = task % 12;
    const float* rr = gx + (bc*24 + 2*kx)*256;
    // FIX(R6): 8 iterations, not 16 — 32 lanes x 8 = 256 y-positions.
    // i<16 ran y to 511: read past the row AND wrote R[g*528+1023],
    // racing into groups g+1/g+2's staging region (the R1-R6 bug).
    for (int i = 0; i < 8; ++i) {
      int y = s + 32*i;
      R[g*528 + 2*y]     = rr[y];
      R[g*528 + 2*y + 1] = rr[256 + y];
    }
  }
  __syncthreads();
  if (s < 24) {
    const int kyv = (s < 12) ? s : (232 + s);
    float ar = 0.f, ai = 0.f;
    int tt = 0;
    const float* Rg = &R[g*528];
    for (int y = 0; y < 256; ++y) {
      float2 v = *(const float2*)&Rg[2*y];
      float2 w = *(const float2*)&csl[2*tt];
      ar += v.x*w.x + v.y*w.y;      // v * conj(e^{i theta})
      ai += v.y*w.x - v.x*w.y;
      tt = (tt + kyv) & 255;
    }
    int bc = task / 12, kx = task % 12;
    int b = bc >> 5, ch = bc & 31;
    float* o = fc + ((b*24 + s)*12 + kx)*64 + 2*ch;
    o[0] = ar; o[1] = ai;
  }
}

// Per-mode complex channel mix: out[b,o] = sum_i fin[b,i] * w[i,o]
__global__ __launch_bounds__(256) void k_mix(
    const float* __restrict__ fc, float* __restrict__ fm,
    const float* __restrict__ w1r, const float* __restrict__ w1i,
    const float* __restrict__ w2r, const float* __restrict__ w2i)
{
  const int ky = blockIdx.x / 12, kx = blockIdx.x % 12;
  const int tid = threadIdx.x;
  __shared__ float wre[1024], wim[1024];
  __shared__ float fin[1024];
  const float* wr_ = (ky < 12) ? w1r : w2r;
  const float* wi_ = (ky < 12) ? w1i : w2i;
  const int kyp = (ky < 12) ? ky : ky - 12;
  for (int f = tid; f < 1024; f += 256) {
    int idx = f*144 + kyp*12 + kx;
    wre[f] = wr_[idx]; wim[f] = wi_[idx];
  }
  for (int f = tid; f < 1024; f += 256) {
    int b = f >> 6, j = f & 63;
    fin[f] = fc[((b*24 + ky)*12 + kx)*64 + j];
  }
  __syncthreads();
  for (int k = 0; k < 2; ++k) {
    int idx = tid + k*256;
    int b = idx >> 5, o = idx & 31;
    float ar = 0.f, ai = 0.f;
    #pragma unroll
    for (int i = 0; i < 32; ++i) {
      float fr = fin[b*64 + 2*i], fi2 = fin[b*64 + 2*i + 1];
      float wr = wre[i*32+o],     wi2 = wim[i*32+o];
      ar += fr*wr - fi2*wi2;
      ai += fr*wi2 + fi2*wr;
    }
    float* op = fm + ((b*24 + ky)*12 + kx)*64 + 2*o;
    op[0] = ar; op[1] = ai;
  }
}

// Inverse DFT along y: 24 modes -> 256 y (full complex ifft, 1/(H*W) folded)
// gy layout [b][y][kx][o][2]
__global__ __launch_bounds__(256) void k_inv_y(
    const float* __restrict__ fm, const float* __restrict__ cs,
    float* __restrict__ gy)
{
  const int b = blockIdx.x / 12, kx = blockIdx.x % 12;
  const int tid = threadIdx.x;
  __shared__ __align__(16) float F[1536];
  __shared__ __align__(16) float csl[512];
  for (int f = tid; f < 1536; f += 256) {
    int s = f >> 6, j = f & 63;
    F[f] = fm[((b*24 + s)*12 + kx)*64 + j];
  }
  for (int f = tid; f < 512; f += 256) csl[f] = cs[f];
  __syncthreads();
  const int y = tid;
  float tc[24], tsn[24];
  #pragma unroll
  for (int s = 0; s < 24; ++s) {
    int kyv = (s < 12) ? s : (232 + s);
    int tt = (kyv * y) & 255;
    tc[s] = csl[2*tt]; tsn[s] = csl[2*tt+1];
  }
  float* orow = gy + ((b*256 + y)*12 + kx)*64;
  for (int o2 = 0; o2 < 16; ++o2) {
    float ar0 = 0.f, ai0 = 0.f, ar1 = 0.f, ai1 = 0.f;
    #pragma unroll
    for (int s = 0; s < 24; ++s) {
      float2 f0 = *(const float2*)&F[s*64 + 4*o2];
      float2 f1 = *(const float2*)&F[s*64 + 4*o2 + 2];
      ar0 += f0.x*tc[s] - f0.y*tsn[s];
      ai0 += f0.x*tsn[s] + f0.y*tc[s];
      ar1 += f1.x*tc[s] - f1.y*tsn[s];
      ai1 += f1.x*tsn[s] + f1.y*tc[s];
    }
    float4 v;
    v.x = ar0*INV_HW; v.y = ai0*INV_HW; v.z = ar1*INV_HW; v.w = ai1*INV_HW;
    *(float4*)(orow + 4*o2) = v;
  }
}

// Inverse DFT along x + residual pointwise linear + ReLU + BN-stat partials.
// block = (b,y); thread = x. z layout [b][o][y][x]; part[block][2c|2c+1]
__global__ __launch_bounds__(256) void k_inv_x_epi(
    const float* __restrict__ gy, const float* __restrict__ cs,
    const float* __restrict__ lw, const float* __restrict__ lb,
    float* __restrict__ z, float* __restrict__ part)
{
  const int b = blockIdx.x >> 8, y = blockIdx.x & 255;
  const int tid = threadIdx.x;
  __shared__ __align__(16) float G[768];
  __shared__ __align__(16) float lwl[1024];
  __shared__ float lbl[32];
  __shared__ __align__(16) float csl[512];
  __shared__ float S[32*257];
  __shared__ float red[64];
  for (int f = tid; f < 768; f += 256)  G[f]   = gy[(b*256 + y)*768 + f];
  for (int f = tid; f < 1024; f += 256) lwl[f] = lw[f];
  if (tid < 32) lbl[tid] = lb[tid];
  for (int f = tid; f < 512; f += 256)  csl[f] = cs[f];
  __syncthreads();
  const int x = tid;
  float tc[12], tsn[12];
  #pragma unroll
  for (int kx = 1; kx < 12; ++kx) {
    int tt = (kx * x) & 255;
    tc[kx]  = 2.0f*csl[2*tt];
    tsn[kx] = 2.0f*csl[2*tt+1];
  }
  float yv[32];
  #pragma unroll
  for (int c = 0; c < 32; ++c) {
    float acc = G[2*c];                       // kx=0: Re only (c2r semantics)
    #pragma unroll
    for (int kx = 1; kx < 12; ++kx)
      acc += G[kx*64 + 2*c]*tc[kx] - G[kx*64 + 2*c + 1]*tsn[kx];
    yv[c] = acc;
  }
  float zv[32];
  const float4* lw4 = (const float4*)lwl;
  #pragma unroll
  for (int o = 0; o < 32; ++o) {
    float a = lbl[o] + yv[o];
    #pragma unroll
    for (int c4 = 0; c4 < 8; ++c4) {
      float4 wv = lw4[o*8 + c4];
      a += yv[4*c4]*wv.x + yv[4*c4+1]*wv.y + yv[4*c4+2]*wv.z + yv[4*c4+3]*wv.w;
    }
    zv[o] = fmaxf(a, 0.0f);
  }
  #pragma unroll
  for (int o = 0; o < 32; ++o)
    z[((b*32 + o)*256 + y)*256 + x] = zv[o];
  // stats via LDS transpose: S[c][x]
  #pragma unroll
  for (int o = 0; o < 32; ++o) S[o*257 + tid] = zv[o];
  __syncthreads();
  {
    int t2 = tid >> 2, p = tid & 3;       // t2 = 2c+issq
    int o = t2 >> 1, issq = t2 & 1;
    const float* Sp = &S[o*257];
    float acc = 0.f;
    if (!issq) {
      for (int j = 0; j < 64; ++j) acc += Sp[p + 4*j];
    } else {
      for (int j = 0; j < 64; ++j) { float v = Sp[p + 4*j]; acc += v*v; }
    }
    acc += __shfl_xor(acc, 1, 64);
    acc += __shfl_xor(acc, 2, 64);
    if (p == 0) red[t2] = acc;
  }
  __syncthreads();
  if (tid < 64) part[(long)blockIdx.x*64 + tid] = red[tid];
}

// Reduce partials -> BN scale/bias for next consumer
__global__ __launch_bounds__(256) void k_stats(
    const float* __restrict__ part, const float* __restrict__ gamma,
    const float* __restrict__ beta, float* __restrict__ bn)
{
  const int c = blockIdx.x, tid = threadIdx.x;
  float s1 = 0.f, s2 = 0.f;
  for (int j = tid; j < 4096; j += 256) {
    s1 += part[(long)j*64 + 2*c];
    s2 += part[(long)j*64 + 2*c + 1];
  }
  #pragma unroll
  for (int d = 32; d; d >>= 1) {
    s1 += __shfl_xor(s1, d, 64);
    s2 += __shfl_xor(s2, d, 64);
  }
  __shared__ float r1[4], r2[4];
  int w = tid >> 6;
  if ((tid & 63) == 0) { r1[w] = s1; r2[w] = s2; }
  __syncthreads();
  if (tid == 0) {
    float S1 = r1[0]+r1[1]+r1[2]+r1[3];
    float S2 = r2[0]+r2[1]+r2[2]+r2[3];
    const float N = 1048576.0f;
    float mean = S1 / N;
    float var  = S2 / N - mean*mean;
    float inv  = rsqrtf(var + 1e-5f);
    float sc   = gamma[c] * inv;
    bn[c]      = sc;
    bn[32 + c] = beta[c] - mean*sc;
  }
}

// Final: BN affine (layer 3) + linear_out
__global__ __launch_bounds__(256) void k_out(
    const float* __restrict__ z, const float* __restrict__ bn,
    const float* __restrict__ w_out, const float* __restrict__ b_out,
    float* __restrict__ out)
{
  __shared__ float a[32];
  __shared__ float c0s;
  const int tid = threadIdx.x;
  if (tid < 32) a[tid] = bn[tid] * w_out[tid];
  if (tid == 0) {
    float t = b_out[0];
    for (int c = 0; c < 32; ++c) t += bn[32 + c] * w_out[c];
    c0s = t;
  }
  __syncthreads();
  int gid = blockIdx.x*256 + tid;             // [0, 262144)
  int b = gid >> 14, pos = (gid & 16383) << 2;
  const float* zb = z + (long)b*2097152 + pos;
  float c0 = c0s;
  float r0 = c0, r1 = c0, r2 = c0, r3 = c0;
  #pragma unroll 8
  for (int c = 0; c < 32; ++c) {
    float4 v = *(const float4*)(zb + c*65536);
    float ac = a[c];
    r0 += v.x*ac; r1 += v.y*ac; r2 += v.z*ac; r3 += v.w*ac;
  }
  float4 res; res.x = r0; res.y = r1; res.z = r2; res.w = r3;
  *(float4*)(out + (long)b*65536 + pos) = res;
}

extern "C" void kernel_launch(void* const* d_in, const int* in_sizes, int n_in,
                              void* d_out, int out_size, void* d_ws, size_t ws_size,
                              hipStream_t stream) {
  const float* x      = (const float*)d_in[0];
  const float* coords = (const float*)d_in[1];
  const float* w_in   = (const float*)d_in[2];
  const float* b_in   = (const float*)d_in[3];
  const float* w1r    = (const float*)d_in[4];
  const float* w1i    = (const float*)d_in[5];
  const float* w2r    = (const float*)d_in[6];
  const float* w2i    = (const float*)d_in[7];
  const float* lw     = (const float*)d_in[8];
  const float* lb     = (const float*)d_in[9];
  const float* gamma  = (const float*)d_in[10];
  const float* beta   = (const float*)d_in[11];
  const float* w_out  = (const float*)d_in[12];
  const float* b_out  = (const float*)d_in[13];
  float* out = (float*)d_out;
  float* ws  = (float*)d_ws;

  float* cs   = ws;
  float* z    = cs + 512;
  float* gxy  = z + 33554432;        // gx (fwd) and gy (inv) share
  float* fc   = gxy + 3145728;       // part (262144) aliases fc (294912)
  float* fm   = fc + 294912;
  float* bn   = fm + 294912;
  float* part = fc;                  // disjoint lifetime with fc

  k_init<<<1, 256, 0, stream>>>(cs);
  k_embed<<<4096, 256, 0, stream>>>(x, coords, w_in, b_in, z);

  for (int l = 0; l < 4; ++l) {
    k_fwd_x<<<4096, 256, 0, stream>>>(z, cs, (l == 0) ? nullptr : bn, gxy);
    k_fwd_y<<<768, 256, 0, stream>>>(gxy, cs, fc);
    k_mix<<<288, 256, 0, stream>>>(fc, fm, w1r + l*147456, w1i + l*147456,
                                   w2r + l*147456, w2i + l*147456);
    k_inv_y<<<192, 256, 0, stream>>>(fm, cs, gxy);
    k_inv_x_epi<<<4096, 256, 0, stream>>>(gxy, cs, lw + l*1024, lb + l*32, z, part);
    k_stats<<<32, 256, 0, stream>>>(part, gamma + l*32, beta + l*32, bn);
  }

  k_out<<<1024, 256, 0, stream>>>(z, bn, w_out, b_out, out);
}

// Round 8
// 864.795 us; speedup vs baseline: 76.7302x; 1.0417x over previous
//
#include <hip/hip_runtime.h>

constexpr double PI2 = 6.283185307179586476925286766559;
constexpr float INV_HW = 1.0f / 65536.0f;

// B=16, D=32, H=W=256, M=12, L=4
// ws (floats), total 37,290,560 (142.25 MiB — proven safe):
//   cs[512] | z[33554432] | gy[3145728] | fc[294912] | fm[294912] | bn[64]
//   gx ALIASES z[0:3145728] (z only written by layer-3 k_fuse, after gx_3 dead)
//   part (262144) ALIASES fc (disjoint lifetimes)

__global__ __launch_bounds__(256) void k_init(float* __restrict__ cs) {
  int t = threadIdx.x;
  double a = PI2 * (double)t / 256.0;
  cs[2*t]   = (float)cos(a);
  cs[2*t+1] = (float)sin(a);
}

// Layer-0 input DFT, fused: h0 computed in registers, x-DFT to 12 modes.
// h0[d] = w_in[d,0]*x + w_in[d,1]*c0 + w_in[d,2]*c1 + b_in[d]
// gx layout [bc][2kx+comp][y]
__global__ __launch_bounds__(256) void k_embed_fwd(
    const float* __restrict__ xin, const float* __restrict__ coords,
    const float* __restrict__ w_in, const float* __restrict__ b_in,
    const float* __restrict__ cs, float* __restrict__ gxo)
{
  __shared__ float wl[96], bl[32];
  __shared__ __align__(16) float csl[512];
  __shared__ float S[32*257];
  const int tid = threadIdx.x;
  if (tid < 96) wl[tid] = w_in[tid];
  if (tid >= 96 && tid < 128) bl[tid-96] = b_in[tid-96];
  for (int f = tid; f < 512; f += 256) csl[f] = cs[f];
  const int b = blockIdx.x >> 8, y = blockIdx.x & 255;
  const float xv = xin[(b*256 + y)*256 + tid];
  const float c0 = coords[y*256 + tid];
  const float c1 = coords[65536 + y*256 + tid];
  __syncthreads();
  #pragma unroll 8
  for (int d = 0; d < 32; ++d)
    S[d*257 + tid] = wl[3*d]*xv + wl[3*d+1]*c0 + wl[3*d+2]*c1 + bl[d];
  __syncthreads();
  const int task = tid >> 5, o = tid & 31;
  if (task < 6) {
    const int kx0 = task*2, kx1 = kx0 + 1;
    float ar0=0.f, ai0=0.f, ar1=0.f, ai1=0.f;
    const float* Sp = &S[o*257];
    int t0 = 0, t1 = 0;
    for (int xx = 0; xx < 256; ++xx) {
      float v = Sp[xx];
      float2 w0 = *(const float2*)&csl[2*t0];
      float2 w1 = *(const float2*)&csl[2*t1];
      ar0 += v*w0.x; ai0 -= v*w0.y;
      ar1 += v*w1.x; ai1 -= v*w1.y;
      t0 = (t0 + kx0) & 255;
      t1 = (t1 + kx1) & 255;
    }
    const int bc = b*32 + o;
    float* p0 = gxo + (bc*24 + 2*kx0)*256;
    p0[y] = ar0; p0[256 + y] = ai0;
    float* p1 = gxo + (bc*24 + 2*kx1)*256;
    p1[y] = ar1; p1[256 + y] = ai1;
  }
}

// Forward DFT along y with BN-affine fold applied on staging:
// X'[kx][y] = sc*X[kx][y] + 256*bias*(kx==0).  bnp==nullptr -> identity.
// fc layout [b][ky24][kx12][C32][2]
__global__ __launch_bounds__(256) void k_fwd_y(
    const float* __restrict__ gx, const float* __restrict__ cs,
    const float* __restrict__ bnp, float* __restrict__ fc)
{
  __shared__ __align__(16) float R[8*528];
  __shared__ __align__(16) float csl[512];
  const int tid = threadIdx.x;
  for (int f = tid; f < 512; f += 256) csl[f] = cs[f];
  const int g = tid >> 5, s = tid & 31;
  const int task = blockIdx.x*8 + g;        // [0, 6144)
  const int bc = task / 12, kx = task % 12;
  {
    const float* rr = gx + (bc*24 + 2*kx)*256;
    float sc = 1.0f, badd = 0.0f;
    if (bnp) {
      int ch = bc & 31;
      sc = bnp[ch];
      badd = (kx == 0) ? 256.0f*bnp[32 + ch] : 0.0f;
    }
    for (int i = 0; i < 8; ++i) {          // 32 lanes x 8 = 256 y (R6 fix)
      int y = s + 32*i;
      R[g*528 + 2*y]     = sc*rr[y] + badd;
      R[g*528 + 2*y + 1] = sc*rr[256 + y];
    }
  }
  __syncthreads();
  if (s < 24) {
    const int kyv = (s < 12) ? s : (232 + s);
    float ar = 0.f, ai = 0.f;
    int tt = 0;
    const float* Rg = &R[g*528];
    for (int y = 0; y < 256; ++y) {
      float2 v = *(const float2*)&Rg[2*y];
      float2 w = *(const float2*)&csl[2*tt];
      ar += v.x*w.x + v.y*w.y;      // v * conj(e^{i theta})
      ai += v.y*w.x - v.x*w.y;
      tt = (tt + kyv) & 255;
    }
    int bb = bc >> 5, ch = bc & 31;
    float* o = fc + ((bb*24 + s)*12 + kx)*64 + 2*ch;
    o[0] = ar; o[1] = ai;
  }
}

// Per-mode complex channel mix: out[b,o] = sum_i fin[b,i] * w[i,o]
__global__ __launch_bounds__(256) void k_mix(
    const float* __restrict__ fc, float* __restrict__ fm,
    const float* __restrict__ w1r, const float* __restrict__ w1i,
    const float* __restrict__ w2r, const float* __restrict__ w2i)
{
  const int ky = blockIdx.x / 12, kx = blockIdx.x % 12;
  const int tid = threadIdx.x;
  __shared__ float wre[1024], wim[1024];
  __shared__ float fin[1024];
  const float* wr_ = (ky < 12) ? w1r : w2r;
  const float* wi_ = (ky < 12) ? w1i : w2i;
  const int kyp = (ky < 12) ? ky : ky - 12;
  for (int f = tid; f < 1024; f += 256) {
    int idx = f*144 + kyp*12 + kx;
    wre[f] = wr_[idx]; wim[f] = wi_[idx];
  }
  for (int f = tid; f < 1024; f += 256) {
    int b = f >> 6, j = f & 63;
    fin[f] = fc[((b*24 + ky)*12 + kx)*64 + j];
  }
  __syncthreads();
  for (int k = 0; k < 2; ++k) {
    int idx = tid + k*256;
    int b = idx >> 5, o = idx & 31;
    float ar = 0.f, ai = 0.f;
    #pragma unroll
    for (int i = 0; i < 32; ++i) {
      float fr = fin[b*64 + 2*i], fi2 = fin[b*64 + 2*i + 1];
      float wr = wre[i*32+o],     wi2 = wim[i*32+o];
      ar += fr*wr - fi2*wi2;
      ai += fr*wi2 + fi2*wr;
    }
    float* op = fm + ((b*24 + ky)*12 + kx)*64 + 2*o;
    op[0] = ar; op[1] = ai;
  }
}

// Inverse DFT along y: 24 modes -> 256 y (full complex ifft, 1/(H*W) folded)
// gy layout [b][y][kx][o][2]
__global__ __launch_bounds__(256) void k_inv_y(
    const float* __restrict__ fm, const float* __restrict__ cs,
    float* __restrict__ gy)
{
  const int b = blockIdx.x / 12, kx = blockIdx.x % 12;
  const int tid = threadIdx.x;
  __shared__ __align__(16) float F[1536];
  __shared__ __align__(16) float csl[512];
  for (int f = tid; f < 1536; f += 256) {
    int s = f >> 6, j = f & 63;
    F[f] = fm[((b*24 + s)*12 + kx)*64 + j];
  }
  for (int f = tid; f < 512; f += 256) csl[f] = cs[f];
  __syncthreads();
  const int y = tid;
  float tc[24], tsn[24];
  #pragma unroll
  for (int s = 0; s < 24; ++s) {
    int kyv = (s < 12) ? s : (232 + s);
    int tt = (kyv * y) & 255;
    tc[s] = csl[2*tt]; tsn[s] = csl[2*tt+1];
  }
  float* orow = gy + ((b*256 + y)*12 + kx)*64;
  for (int o2 = 0; o2 < 16; ++o2) {
    float ar0 = 0.f, ai0 = 0.f, ar1 = 0.f, ai1 = 0.f;
    #pragma unroll
    for (int s = 0; s < 24; ++s) {
      float2 f0 = *(const float2*)&F[s*64 + 4*o2];
      float2 f1 = *(const float2*)&F[s*64 + 4*o2 + 2];
      ar0 += f0.x*tc[s] - f0.y*tsn[s];
      ai0 += f0.x*tsn[s] + f0.y*tc[s];
      ar1 += f1.x*tc[s] - f1.y*tsn[s];
      ai1 += f1.x*tsn[s] + f1.y*tc[s];
    }
    float4 v;
    v.x = ar0*INV_HW; v.y = ai0*INV_HW; v.z = ar1*INV_HW; v.w = ai1*INV_HW;
    *(float4*)(orow + 4*o2) = v;
  }
}

// FUSED: inverse-x DFT + residual linear + ReLU + BN partials + NEXT layer's
// forward-x DFT (z stays in registers/LDS; HBM z write only when z != null).
// block=(b,y); gxo==null for the last layer; z==null except last layer.
__global__ __launch_bounds__(256) void k_fuse(
    const float* __restrict__ gy, const float* __restrict__ cs,
    const float* __restrict__ lw, const float* __restrict__ lb,
    float* __restrict__ gxo, float* __restrict__ part, float* __restrict__ z)
{
  const int b = blockIdx.x >> 8, y = blockIdx.x & 255;
  const int tid = threadIdx.x;
  __shared__ __align__(16) float G[768];
  __shared__ __align__(16) float lwl[1024];
  __shared__ float lbl[32];
  __shared__ __align__(16) float csl[512];
  __shared__ float S[32*257];
  for (int f = tid; f < 768; f += 256)  G[f]   = gy[(b*256 + y)*768 + f];
  for (int f = tid; f < 1024; f += 256) lwl[f] = lw[f];
  if (tid < 32) lbl[tid] = lb[tid];
  for (int f = tid; f < 512; f += 256)  csl[f] = cs[f];
  __syncthreads();
  const int x = tid;
  float tc[12], tsn[12];
  #pragma unroll
  for (int kx = 1; kx < 12; ++kx) {
    int tt = (kx * x) & 255;
    tc[kx]  = 2.0f*csl[2*tt];
    tsn[kx] = 2.0f*csl[2*tt+1];
  }
  float yv[32];
  #pragma unroll
  for (int c = 0; c < 32; c += 2) {       // c2r: kx=0 Re only, 2x for kx>=1
    float a0 = G[2*c];
    float a1 = G[2*c + 2];
    #pragma unroll
    for (int kx = 1; kx < 12; ++kx) {
      float4 g = *(const float4*)&G[kx*64 + 2*c];
      a0 += g.x*tc[kx] - g.y*tsn[kx];
      a1 += g.z*tc[kx] - g.w*tsn[kx];
    }
    yv[c] = a0; yv[c+1] = a1;
  }
  float zv[32];
  const float4* lw4 = (const float4*)lwl;
  #pragma unroll
  for (int o = 0; o < 32; ++o) {
    float a = lbl[o] + yv[o];
    #pragma unroll
    for (int c4 = 0; c4 < 8; ++c4) {
      float4 wv = lw4[o*8 + c4];
      a += yv[4*c4]*wv.x + yv[4*c4+1]*wv.y + yv[4*c4+2]*wv.z + yv[4*c4+3]*wv.w;
    }
    zv[o] = fmaxf(a, 0.0f);
  }
  if (z) {
    #pragma unroll
    for (int o = 0; o < 32; ++o)
      z[((b*32 + o)*256 + y)*256 + x] = zv[o];
  }
  #pragma unroll
  for (int o = 0; o < 32; ++o) S[o*257 + tid] = zv[o];
  __syncthreads();
  // phase B: 8 tasks x 32 channels. tasks 0-5: kx pair dots (task0's kx=0
  // real part IS the BN sum); tasks 6,7: sumsq halves.
  const int task = tid >> 5, o = tid & 31;
  if (task < 6) {
    if (gxo || task == 0) {
      const int kx0 = task*2, kx1 = kx0 + 1;
      float ar0=0.f, ai0=0.f, ar1=0.f, ai1=0.f;
      const float* Sp = &S[o*257];
      int t0 = 0, t1 = 0;
      for (int xx = 0; xx < 256; ++xx) {
        float v = Sp[xx];
        float2 w0 = *(const float2*)&csl[2*t0];
        float2 w1 = *(const float2*)&csl[2*t1];
        ar0 += v*w0.x; ai0 -= v*w0.y;
        ar1 += v*w1.x; ai1 -= v*w1.y;
        t0 = (t0 + kx0) & 255;
        t1 = (t1 + kx1) & 255;
      }
      if (task == 0) part[(long)blockIdx.x*64 + 2*o] = ar0;   // channel sum
      if (gxo) {
        const int bc = b*32 + o;
        float* p0 = gxo + (bc*24 + 2*kx0)*256;
        p0[y] = ar0; p0[256 + y] = ai0;
        float* p1 = gxo + (bc*24 + 2*kx1)*256;
        p1[y] = ar1; p1[256 + y] = ai1;
      }
    }
  } else {
    const int xb = (task - 6) << 7;
    const float* Sp = &S[o*257];
    float sq = 0.f;
    for (int j = 0; j < 128; ++j) { float v = Sp[xb + j]; sq += v*v; }
    sq += __shfl_xor(sq, 32, 64);          // combine task6+task7 (same wave)
    if (task == 6) part[(long)blockIdx.x*64 + 2*o + 1] = sq;
  }
}

// Reduce partials -> BN scale/bias for next consumer
__global__ __launch_bounds__(256) void k_stats(
    const float* __restrict__ part, const float* __restrict__ gamma,
    const float* __restrict__ beta, float* __restrict__ bn)
{
  const int c = blockIdx.x, tid = threadIdx.x;
  float s1 = 0.f, s2 = 0.f;
  for (int j = tid; j < 4096; j += 256) {
    s1 += part[(long)j*64 + 2*c];
    s2 += part[(long)j*64 + 2*c + 1];
  }
  #pragma unroll
  for (int d = 32; d; d >>= 1) {
    s1 += __shfl_xor(s1, d, 64);
    s2 += __shfl_xor(s2, d, 64);
  }
  __shared__ float r1[4], r2[4];
  int w = tid >> 6;
  if ((tid & 63) == 0) { r1[w] = s1; r2[w] = s2; }
  __syncthreads();
  if (tid == 0) {
    float S1 = r1[0]+r1[1]+r1[2]+r1[3];
    float S2 = r2[0]+r2[1]+r2[2]+r2[3];
    const float N = 1048576.0f;
    float mean = S1 / N;
    float var  = S2 / N - mean*mean;
    float inv  = rsqrtf(var + 1e-5f);
    float sc   = gamma[c] * inv;
    bn[c]      = sc;
    bn[32 + c] = beta[c] - mean*sc;
  }
}

// Final: BN affine (layer 3) + linear_out
__global__ __launch_bounds__(256) void k_out(
    const float* __restrict__ z, const float* __restrict__ bn,
    const float* __restrict__ w_out, const float* __restrict__ b_out,
    float* __restrict__ out)
{
  __shared__ float a[32];
  __shared__ float c0s;
  const int tid = threadIdx.x;
  if (tid < 32) a[tid] = bn[tid] * w_out[tid];
  if (tid == 0) {
    float t = b_out[0];
    for (int c = 0; c < 32; ++c) t += bn[32 + c] * w_out[c];
    c0s = t;
  }
  __syncthreads();
  int gid = blockIdx.x*256 + tid;             // [0, 262144)
  int b = gid >> 14, pos = (gid & 16383) << 2;
  const float* zb = z + (long)b*2097152 + pos;
  float c0 = c0s;
  float r0 = c0, r1 = c0, r2 = c0, r3 = c0;
  #pragma unroll 8
  for (int c = 0; c < 32; ++c) {
    float4 v = *(const float4*)(zb + c*65536);
    float ac = a[c];
    r0 += v.x*ac; r1 += v.y*ac; r2 += v.z*ac; r3 += v.w*ac;
  }
  float4 res; res.x = r0; res.y = r1; res.z = r2; res.w = r3;
  *(float4*)(out + (long)b*65536 + pos) = res;
}

extern "C" void kernel_launch(void* const* d_in, const int* in_sizes, int n_in,
                              void* d_out, int out_size, void* d_ws, size_t ws_size,
                              hipStream_t stream) {
  const float* x      = (const float*)d_in[0];
  const float* coords = (const float*)d_in[1];
  const float* w_in   = (const float*)d_in[2];
  const float* b_in   = (const float*)d_in[3];
  const float* w1r    = (const float*)d_in[4];
  const float* w1i    = (const float*)d_in[5];
  const float* w2r    = (const float*)d_in[6];
  const float* w2i    = (const float*)d_in[7];
  const float* lw     = (const float*)d_in[8];
  const float* lb     = (const float*)d_in[9];
  const float* gamma  = (const float*)d_in[10];
  const float* beta   = (const float*)d_in[11];
  const float* w_out  = (const float*)d_in[12];
  const float* b_out  = (const float*)d_in[13];
  float* out = (float*)d_out;
  float* ws  = (float*)d_ws;

  float* cs   = ws;
  float* z    = cs + 512;            // gx aliases z[0:3145728]
  float* gx   = z;
  float* gy   = z + 33554432;
  float* fc   = gy + 3145728;        // part aliases fc
  float* fm   = fc + 294912;
  float* bn   = fm + 294912;
  float* part = fc;
  // total 37,290,560 floats = 142.25 MiB (same as passing R7)

  k_init<<<1, 256, 0, stream>>>(cs);
  k_embed_fwd<<<4096, 256, 0, stream>>>(x, coords, w_in, b_in, cs, gx);

  for (int l = 0; l < 4; ++l) {
    k_fwd_y<<<768, 256, 0, stream>>>(gx, cs, (l == 0) ? nullptr : bn, fc);
    k_mix<<<288, 256, 0, stream>>>(fc, fm, w1r + l*147456, w1i + l*147456,
                                   w2r + l*147456, w2i + l*147456);
    k_inv_y<<<192, 256, 0, stream>>>(fm, cs, gy);
    k_fuse<<<4096, 256, 0, stream>>>(gy, cs, lw + l*1024, lb + l*32,
                                     (l < 3) ? gx : nullptr, part,
                                     (l == 3) ? z : nullptr);
    k_stats<<<32, 256, 0, stream>>>(part, gamma + l*32, beta + l*32, bn);
  }

  k_out<<<1024, 256, 0, stream>>>(z, bn, w_out, b_out, out);
}